// Round 1
// baseline (177.784 us; speedup 1.0000x reference)
//
#include <hip/hip_runtime.h>
#include <hip/hip_bf16.h>
#include <stdint.h>

#define BATCH 64
#define CIN   64
#define LEN   4096
#define COUT  128
#define KW    7
#define LPOOL 2048
#define NT    4     // l sub-tiles of 64 per block
#define RROWS 72    // sign rows: p = l0-4+r, r in [0,72)
#define RAWP  80    // raw floats per ci row: p = l0-8+col, col in [0,80)
#define SPITCH 64   // ushorts per stg row = 128B (XOR-swizzled by (r&7)<<4 bytes)

typedef __bf16 v8bf __attribute__((ext_vector_type(8)));
typedef unsigned short v8us __attribute__((ext_vector_type(8)));
typedef float  v4f  __attribute__((ext_vector_type(4)));

typedef const __attribute__((address_space(1))) void* gp1_t;
typedef __attribute__((address_space(3))) void* lp3_t;

// Convert conv_w [COUT][CIN][KW] fp32 -> Wt [KW][COUT][CIN] bf16 (RNE).
__global__ __launch_bounds__(256)
void wconv_kernel(const float* __restrict__ W, ushort* __restrict__ Wt) {
    int i = blockIdx.x * 256 + threadIdx.x;
    if (i >= COUT * CIN * KW) return;
    int co  = i / (CIN * KW);
    int rem = i - co * (CIN * KW);
    int ci  = rem / KW;
    int k   = rem - ci * KW;
    uint u = __float_as_uint(W[i]);
    uint r = (u + 0x7FFFu + ((u >> 16) & 1u)) >> 16;   // RNE to bf16
    Wt[(k * COUT + co) * CIN + ci] = (ushort)r;
}

// Fused: BN -> sign -> conv (bf16 MFMA) -> alpha -> PReLU -> maxpool2.
// R7 (this round) — latency-bound diagnosis (all pipes <= ~33% of the
// 206K-cycle wall): attack serialized stalls, keep structure.
//   (1) W-frag double-buffer rotation: W is t-invariant, k cyclic. Prefetch
//       k+1 (k=6 -> k=0 for next t) into n** regs during k's MFMAs; the
//       vmcnt wait lands on the end-of-iter rotation copies, after the MFMAs.
//       Removes 7 exposed global-load round-trips per wave-t.
//   (2) stg: 128B pitch + XOR swizzle byte^=(r&7)<<4 (m214-verified pattern)
//       to kill the 3.67M measured bank-conflict cycles. (r&7) is
//       mt-invariant (16mt==0 mod 8), so mt offsets stay ds_read immediates.
//   (3) binarize: BN consts hoisted to 24 regs (t-invariant); raw read as
//       float4 (8 x b128/thread, 144 active threads of 256) instead of 24
//       scalar b32 + 24 bnc b128 per thread.
// Pipeline/tile unchanged: binarize(t) | barrier | DMA(t+1) | MFMA(t)+stores | barrier.
__global__ __launch_bounds__(256, 3)
void conv_kernel(const float* __restrict__ I,
                 const float* __restrict__ bn_g, const float* __restrict__ bn_b,
                 const float* __restrict__ bn_m, const float* __restrict__ bn_v,
                 const ushort* __restrict__ Wt,
                 const float* __restrict__ alpha, const float* __restrict__ prelu,
                 float* __restrict__ out) {
    __shared__ __attribute__((aligned(16))) float  raw[CIN * RAWP];      // 20480 B
    __shared__ __attribute__((aligned(16))) ushort stg[RROWS * SPITCH];  // 9216 B

    int tid = threadIdx.x;
    int lane = tid & 63, wave = tid >> 6;
    int b = blockIdx.y, bx = blockIdx.x;
    int l0base = bx * (64 * NT);

    const float* Ib = I + (size_t)b * CIN * LEN;

    // DMA plan: slot s = wave*5+i covers chunks n = s*64+lane; chunk n = ci*20+c
    // lands at raw float index n*4 = ci*80 + 4c; global p = l0-8+4c+(0..3).
    const char* gb[5]; int cb[5];
    #pragma unroll
    for (int i = 0; i < 5; ++i) {
        int n = (wave * 5 + i) * 64 + lane;
        int ci = n / 20;
        int c  = n - 20 * ci;
        cb[i] = 16 * c - 32;                                  // byte offset before +4*l0
        gb[i] = (const char*)(Ib + (size_t)ci * LEN) + cb[i];
    }

    {   // DMA tile 0
        int l4 = 4 * l0base;
        #pragma unroll
        for (int i = 0; i < 5; ++i) {
            int off = cb[i] + l4;
            if (off >= 0 && off + 16 <= LEN * 4)
                __builtin_amdgcn_global_load_lds((gp1_t)(gb[i] + l4),
                                                 (lp3_t)(raw + (wave * 5 + i) * 256), 16, 0, 0);
        }
    }

    // ---- per-thread BN consts (t-invariant): tid<144 owns ci 8*(tid&7)+.. ----
    int brq  = tid >> 3;        // p-quad row group, active < 18
    int bg8  = tid & 7;         // ci chunk
    int bci0 = bg8 * 8;
    float sc[8], mn[8], bt[8];
    if (tid < 144) {
        #pragma unroll
        for (int c = 0; c < 8; ++c) {
            int ci = bci0 + c;
            // bit-exact vs np fp32: gamma / sqrt(var + eps)
            sc[c] = __fdiv_rn(bn_g[ci], __fsqrt_rn(__fadd_rn(bn_v[ci], 1e-5f)));
            mn[c] = bn_m[ci];
            bt[c] = bn_b[ci];
        }
    }

    int quad = lane >> 4, lr = lane & 15;
    int cout0 = wave * 32;
    const ushort* wbase = Wt + ((size_t)cout0 + lr) * CIN + quad * 8;
    float pw  = prelu[0];
    float al0 = alpha[cout0 + lr];
    float al1 = alpha[cout0 + 16 + lr];
    float* obase = out + ((size_t)b * COUT) * LPOOL + bx * (32 * NT);

    // W k=0 preload (t-invariant; rotation keeps steady state across t)
    v8bf c00 = *(const v8bf*)(wbase);
    v8bf c01 = *(const v8bf*)(wbase + 16 * CIN);
    v8bf c10 = *(const v8bf*)(wbase + 32);
    v8bf c11 = *(const v8bf*)(wbase + 32 + 16 * CIN);

    __syncthreads();   // DMA(0) drained (vmcnt(0) at barrier)

    const float4* raw4 = (const float4*)raw;

    for (int t = 0; t < NT; ++t) {
        int l0 = l0base + t * 64;

        // ---- binarize raw -> stg (vectorized, swizzled writes) ----
        if (tid < 144) {
            float4 fr[8];
            #pragma unroll
            for (int c = 0; c < 8; ++c)
                fr[c] = raw4[(bci0 + c) * (RAWP / 4) + brq + 1];
            #pragma unroll
            for (int j = 0; j < 4; ++j) {
                int r = 4 * brq + j;
                int p = l0 - 4 + r;
                bool pok = (p >= 0) && (p < LEN);
                v8us u;
                #pragma unroll
                for (int c = 0; c < 8; ++c) {
                    float v = ((const float*)&fr[c])[j];
                    // (v - mean) * scale + beta, exact np rounding (sign boundary)
                    float x = __fadd_rn(__fmul_rn(__fsub_rn(v, mn[c]), sc[c]), bt[c]);
                    ushort s = x > 0.f ? (ushort)0x3F80 : (x < 0.f ? (ushort)0xBF80 : (ushort)0);
                    u[c] = pok ? s : (ushort)0;
                }
                *(v8us*)(&stg[r * SPITCH + ((bg8 ^ (r & 7)) << 3)]) = u;
            }
        }
        __syncthreads();   // stg visible; raw free for next DMA

        if (t + 1 < NT) {  // DMA(t+1) flies under MFMA(t)
            int l4 = 4 * (l0 + 64);
            #pragma unroll
            for (int i = 0; i < 5; ++i) {
                int off = cb[i] + l4;
                if (off >= 0 && off + 16 <= LEN * 4)
                    __builtin_amdgcn_global_load_lds((gp1_t)(gb[i] + l4),
                                                     (lp3_t)(raw + (wave * 5 + i) * 256), 16, 0, 0);
            }
        }

        // ---- MFMA(t): k-loop unroll 1, W double-buffered in regs ----
        v4f acc[4][2];
        #pragma unroll
        for (int mt = 0; mt < 4; ++mt) { acc[mt][0] = (v4f)0.f; acc[mt][1] = (v4f)0.f; }

        #pragma unroll 1
        for (int k = 0; k < KW; ++k) {
            // prefetch next tap's W (k=6 wraps to k=0 for next t)
            int nk = (k == KW - 1) ? 0 : k + 1;
            const ushort* wn = wbase + nk * COUT * CIN;
            v8bf n00 = *(const v8bf*)(wn);
            v8bf n01 = *(const v8bf*)(wn + 16 * CIN);
            v8bf n10 = *(const v8bf*)(wn + 32);
            v8bf n11 = *(const v8bf*)(wn + 32 + 16 * CIN);

            // A row for output l=mt*16+lr at tap k: r = l + k + 1; (r&7) mt-invariant
            int rk = lr + 1 + k;
            int s8 = rk & 7;
            const ushort* a0p = &stg[rk * SPITCH + ((quad ^ s8) << 3)];        // ci 0..31 slice
            const ushort* a1p = &stg[rk * SPITCH + (((quad ^ 4) ^ s8) << 3)];  // ci 32..63 slice
            #pragma unroll
            for (int mt = 0; mt < 4; ++mt) {
                v8bf a0 = *(const v8bf*)(a0p + mt * 16 * SPITCH);
                v8bf a1 = *(const v8bf*)(a1p + mt * 16 * SPITCH);
                acc[mt][0] = __builtin_amdgcn_mfma_f32_16x16x32_bf16(a0, c00, acc[mt][0], 0, 0, 0);
                acc[mt][1] = __builtin_amdgcn_mfma_f32_16x16x32_bf16(a0, c01, acc[mt][1], 0, 0, 0);
                acc[mt][0] = __builtin_amdgcn_mfma_f32_16x16x32_bf16(a1, c10, acc[mt][0], 0, 0, 0);
                acc[mt][1] = __builtin_amdgcn_mfma_f32_16x16x32_bf16(a1, c11, acc[mt][1], 0, 0, 0);
            }
            // rotate: vmcnt wait for n** lands here, after the MFMAs
            c00 = n00; c01 = n01; c10 = n10; c11 = n11;
        }

        // ---- epilogue(t): alpha * PReLU, in-lane pool, float2 stores ----
        float* ob = obase + t * 32;
        #pragma unroll
        for (int n2 = 0; n2 < 2; ++n2) {
            float al = n2 ? al1 : al0;
            int co = cout0 + n2 * 16 + lr;
            float* oc = ob + (size_t)co * LPOOL + quad * 2;
            #pragma unroll
            for (int mt = 0; mt < 4; ++mt) {
                float v0 = acc[mt][n2][0] * al; v0 = v0 > 0.f ? v0 : pw * v0;
                float v1 = acc[mt][n2][1] * al; v1 = v1 > 0.f ? v1 : pw * v1;
                float v2 = acc[mt][n2][2] * al; v2 = v2 > 0.f ? v2 : pw * v2;
                float v3 = acc[mt][n2][3] * al; v3 = v3 > 0.f ? v3 : pw * v3;
                *(float2*)(oc + mt * 8) = make_float2(fmaxf(v0, v1), fmaxf(v2, v3));
            }
        }
        __syncthreads();   // drains DMA(t+1); protects stg until MFMA done
    }
}

extern "C" void kernel_launch(void* const* d_in, const int* in_sizes, int n_in,
                              void* d_out, int out_size, void* d_ws, size_t ws_size,
                              hipStream_t stream) {
    const float* I      = (const float*)d_in[0];
    const float* bn_g   = (const float*)d_in[1];
    const float* bn_b   = (const float*)d_in[2];
    const float* bn_m   = (const float*)d_in[3];
    const float* bn_v   = (const float*)d_in[4];
    const float* conv_w = (const float*)d_in[5];
    const float* alpha  = (const float*)d_in[6];
    const float* prelu  = (const float*)d_in[7];
    float* out = (float*)d_out;

    ushort* Wt = (ushort*)d_ws;   // 7*128*64*2 = 114688 bytes

    wconv_kernel<<<(COUT * CIN * KW + 255) / 256, 256, 0, stream>>>(conv_w, Wt);
    dim3 grid(LEN / (64 * NT), BATCH);
    conv_kernel<<<grid, 256, 0, stream>>>(I, bn_g, bn_b, bn_m, bn_v, Wt, alpha, prelu, out);
}